// Round 1
// baseline (122.064 us; speedup 1.0000x reference)
//
#include <hip/hip_runtime.h>

#define N 2048
#define NTHREADS 256
#define MAXC 1024
#define HEIGHT 0.1f
#define PROM 0.05f
#define MINDIST 10   // suppress |i-j| < 10, i.e. +-9

__global__ __launch_bounds__(NTHREADS)
void peak_kernel(const float* __restrict__ x, float* __restrict__ out) {
    __shared__ float xs[N];
    __shared__ unsigned long long skey[MAXC];
    __shared__ unsigned char sup[N];
    __shared__ unsigned char keepf[N];
    __shared__ float bmin[64], bmax[64];
    __shared__ float wmin[4], wmax[4];
    __shared__ int cnt;

    const int row = blockIdx.x;
    const int tid = threadIdx.x;
    const float* xr = x + row * N;

    // ---- 1. load + exact min/max reduce + normalize ----
    float vals[8];
    float lmin = 3.4e38f, lmax = -3.4e38f;
    const int base = tid * 8;
    #pragma unroll
    for (int e = 0; e < 8; ++e) {
        float v = xr[base + e];
        vals[e] = v;
        lmin = fminf(lmin, v);
        lmax = fmaxf(lmax, v);
    }
    #pragma unroll
    for (int off = 32; off > 0; off >>= 1) {
        lmin = fminf(lmin, __shfl_xor(lmin, off, 64));
        lmax = fmaxf(lmax, __shfl_xor(lmax, off, 64));
    }
    const int wave = tid >> 6;
    const int lane = tid & 63;
    if (lane == 0) { wmin[wave] = lmin; wmax[wave] = lmax; }
    __syncthreads();
    const float xmin = fminf(fminf(wmin[0], wmin[1]), fminf(wmin[2], wmin[3]));
    const float xmax = fmaxf(fmaxf(wmax[0], wmax[1]), fmaxf(wmax[2], wmax[3]));
    const float denom = (xmax - xmin) + 1e-5f;
    #pragma unroll
    for (int e = 0; e < 8; ++e) {
        // IEEE f32 division, exactly as the reference (no rcp-mul!)
        xs[base + e] = (vals[e] - xmin) / denom;
    }
    if (tid == 0) cnt = 0;
    #pragma unroll
    for (int e = 0; e < MAXC / NTHREADS; ++e) skey[tid + e * NTHREADS] = 0ULL;
    #pragma unroll
    for (int e = 0; e < 8; ++e) { sup[base + e] = 0; keepf[base + e] = 0; }
    __syncthreads();

    // ---- 2. candidates: strict local max & height, pack (val, pos) keys ----
    #pragma unroll
    for (int e = 0; e < 8; ++e) {
        int i = base + e;
        if (i >= 1 && i <= N - 2) {
            float v = xs[i];
            if (v > xs[i - 1] && v > xs[i + 1] && v >= HEIGHT) {
                // xn >= 0 always, so raw float bits are order-monotonic.
                // low bits: (N-1-i) so ties (equal value) sort smaller index first
                unsigned long long key =
                    ((unsigned long long)__float_as_uint(v) << 32) |
                    (unsigned long long)(unsigned)(N - 1 - i);
                int slot = atomicAdd(&cnt, 1);
                if (slot < MAXC) skey[slot] = key;
            }
        }
    }
    // 32-wide block min/max summaries (for prominence scans)
    if (tid < 64) {
        float bm = 3.4e38f, bM = -3.4e38f;
        const int s = tid << 5;
        for (int j = 0; j < 32; ++j) {
            float v = xs[s + j];
            bm = fminf(bm, v);
            bM = fmaxf(bM, v);
        }
        bmin[tid] = bm; bmax[tid] = bM;
    }
    __syncthreads();
    const int nc = cnt < MAXC ? cnt : MAXC;

    // ---- 3. bitonic sort of 1024 keys, descending ----
    for (unsigned k = 2; k <= MAXC; k <<= 1) {
        for (unsigned j = k >> 1; j > 0; j >>= 1) {
            #pragma unroll
            for (int e = 0; e < MAXC / NTHREADS; ++e) {
                int i = tid + e * NTHREADS;
                int p = i ^ (int)j;
                if (p > i) {
                    unsigned long long a = skey[i], b = skey[p];
                    bool desc = ((i & (int)k) == 0);
                    if ((a < b) == desc) { skey[i] = b; skey[p] = a; }
                }
            }
            __syncthreads();
        }
    }

    // ---- 4. greedy distance suppression (highest first), wave-0 chunks ----
    const int nchunks = (nc + 63) / 64;
    for (int c = 0; c < nchunks; ++c) {
        if (tid < 64) {  // exactly wave 0
            int kk = c * 64 + tid;
            bool valid = kk < nc;
            unsigned long long key = valid ? skey[kk] : 0ULL;
            int pos = valid ? (N - 1 - (int)(key & 0xFFFFFFFFULL)) : -1000000;
            bool active = valid && (sup[pos] == 0);
            unsigned long long mask = __ballot(active);
            bool kept = false;
            while (mask) {
                int leader = __builtin_ctzll(mask);   // = highest value / smallest idx
                int lpos = __shfl(pos, leader, 64);
                if (tid == leader) kept = true;
                unsigned long long nearm =
                    __ballot(pos >= lpos - (MINDIST - 1) && pos <= lpos + (MINDIST - 1));
                mask &= ~nearm;  // drops leader (dist 0) and its suppressed neighbors
            }
            if (kept) {
                keepf[pos] = 1;
                int lo = pos - (MINDIST - 1); if (lo < 0) lo = 0;
                int hi = pos + (MINDIST - 1); if (hi > N - 1) hi = N - 1;
                for (int j2 = lo; j2 <= hi; ++j2) sup[j2] = 1;
            }
        }
        __syncthreads();  // publish sup[] to next chunk
    }

    // ---- 5. prominence for kept peaks + write output ----
    float* outr = out + row * N;
    for (int idx = tid; idx < N; idx += NTHREADS) {
        float r = 0.0f;
        if (keepf[idx]) {
            float v = xs[idx];
            const int blk = idx >> 5;
            const int bs = blk << 5;
            // left: min over (L, idx], L = last j<idx with xs[j] > v
            float m = v;
            int j2 = idx - 1;
            bool stopped = false;
            for (; j2 >= bs; --j2) {
                float xv = xs[j2];
                if (xv > v) { stopped = true; break; }
                m = fminf(m, xv);
            }
            if (!stopped) {
                for (int b = blk - 1; b >= 0; --b) {
                    if (bmax[b] > v) {
                        for (j2 = (b << 5) + 31; ; --j2) {
                            float xv = xs[j2];
                            if (xv > v) break;
                            m = fminf(m, xv);
                        }
                        break;
                    } else {
                        m = fminf(m, bmin[b]);
                    }
                }
            }
            const float lmin2 = m;
            // right: min over [idx, R), R = first j>idx with xs[j] > v
            m = v;
            stopped = false;
            const int be = bs + 31;
            j2 = idx + 1;
            for (; j2 <= be; ++j2) {
                float xv = xs[j2];
                if (xv > v) { stopped = true; break; }
                m = fminf(m, xv);
            }
            if (!stopped) {
                for (int b = blk + 1; b < 64; ++b) {
                    if (bmax[b] > v) {
                        for (j2 = (b << 5); ; ++j2) {
                            float xv = xs[j2];
                            if (xv > v) break;
                            m = fminf(m, xv);
                        }
                        break;
                    } else {
                        m = fminf(m, bmin[b]);
                    }
                }
            }
            const float rmin2 = m;
            const float prom = v - fmaxf(lmin2, rmin2);
            r = (prom >= PROM) ? 1.0f : 0.0f;
        }
        outr[idx] = r;
    }
}

extern "C" void kernel_launch(void* const* d_in, const int* in_sizes, int n_in,
                              void* d_out, int out_size, void* d_ws, size_t ws_size,
                              hipStream_t stream) {
    const float* x = (const float*)d_in[0];
    float* outp = (float*)d_out;
    const int rows = in_sizes[0] / N;
    peak_kernel<<<rows, NTHREADS, 0, stream>>>(x, outp);
}